// Round 5
// baseline (1647.867 us; speedup 1.0000x reference)
//
#include <hip/hip_runtime.h>
#include <hip/hip_bf16.h>
#include <math.h>

typedef __bf16 bf16x8 __attribute__((ext_vector_type(8)));
typedef __bf16 bf16x4 __attribute__((ext_vector_type(4)));
typedef float f32x4 __attribute__((ext_vector_type(4)));

constexpr int D  = 128;
constexpr int LQ = 2048;
constexpr int SK = 2048;
constexpr int BM = 64;   // queries per block (4 waves x 16 rows)
constexpr int BN = 64;   // keys per iteration
constexpr int PS_STRIDE = 72;
constexpr int NKV = 16;  // B*H distinct KV heads

// ---- prologue A: K fp32 -> Khi/Klo bf16 (elementwise, coalesced)
__global__ __launch_bounds__(256) void conv_k(const float* __restrict__ k,
                                              __bf16* __restrict__ khi,
                                              __bf16* __restrict__ klo) {
  const size_t i = ((size_t)blockIdx.x * 256 + threadIdx.x) * 4;
  f32x4 a = *(const f32x4*)(k + i);
  bf16x4 hi, lo;
#pragma unroll
  for (int j = 0; j < 4; ++j) {
    hi[j] = (__bf16)a[j];
    lo[j] = (__bf16)(a[j] - (float)hi[j]);
  }
  *(bf16x4*)(khi + i) = hi;
  *(bf16x4*)(klo + i) = lo;
}

// ---- prologue B: V fp32 [bh][s][d] -> Vt bf16 [bh][d][s] (reads coalesced)
__global__ __launch_bounds__(256) void transpose_v(const float* __restrict__ v,
                                                   __bf16* __restrict__ vt) {
  const int b    = blockIdx.x;        // 1024 = 16 bh x 64
  const int bh   = b >> 6;
  const int blk2 = b & 63;
  const int t    = threadIdx.x;
  const int s0   = (blk2 * 2 + (t >> 7)) * 16;
  const int d    = t & 127;
  const float* src = v + ((size_t)bh * SK + s0) * D + d;  // stride-D column reads, lanes coalesce over d
  bf16x8 o0, o1;
#pragma unroll
  for (int j = 0; j < 8; ++j) o0[j] = (__bf16)src[j * D];
#pragma unroll
  for (int j = 0; j < 8; ++j) o1[j] = (__bf16)src[(8 + j) * D];
  __bf16* dst = vt + ((size_t)bh * D + d) * SK + s0;
  *(bf16x8*)dst = o0;
  *(bf16x8*)(dst + 8) = o1;
}

// ---- main: barrier-free flash GQA. bf16 MFMA, hi/lo split QK^T (3 MFMAs).
// Layouts (m89/m91/m120): A[m=lane&15][k=quad*8+j]; B[k=quad*8+j][n=lane&15];
// C/D: row=4*quad+r, col=lane&15.
__global__ __launch_bounds__(256, 2)
void gqa_fwd(const float* __restrict__ qg, const __bf16* __restrict__ khi_g,
             const __bf16* __restrict__ klo_g, const __bf16* __restrict__ vt_g,
             float* __restrict__ outg)
{
  __shared__ alignas(16) __bf16 Ps[BM * PS_STRIDE];  // wave-local rows only

  // XCD swizzle: dispatch round-robins bid%8 over XCDs; keep all 32 qtiles
  // of one bhg on one XCD so its 1.5MB of K/V stays L2-resident.
  const int bid   = blockIdx.x;
  const int x     = bid & 7;
  const int r     = bid >> 3;
  const int bhg   = x + 8 * (r >> 5);   // 0..63
  const int qtile = r & 31;
  const int bh    = bhg >> 2;

  const int tid  = threadIdx.x;
  const int wave = tid >> 6;
  const int lane = tid & 63;
  const int i16  = lane & 15;
  const int quad = lane >> 4;

  const float*  qbase = qg + (size_t)bhg * (LQ * D) + (size_t)(qtile * BM) * D;
  const __bf16* khb   = khi_g + (size_t)bh * (SK * D);
  const __bf16* klb   = klo_g + (size_t)bh * (SK * D);
  const __bf16* vtb   = vt_g + (size_t)bh * (D * SK);   // [d][s]

  // ---- Q fragments, persistent hi/lo (wave w owns rows [16w,16w+16))
  bf16x8 qhi[4], qlo[4];
  {
    const float* qp = qbase + (size_t)(16 * wave + i16) * D + 8 * quad;
#pragma unroll
    for (int t = 0; t < 4; ++t) {
      f32x4 a = *(const f32x4*)(qp + 32 * t);
      f32x4 b = *(const f32x4*)(qp + 32 * t + 4);
#pragma unroll
      for (int j = 0; j < 4; ++j) {
        qhi[t][j]     = (__bf16)a[j];
        qlo[t][j]     = (__bf16)(a[j] - (float)qhi[t][j]);
        qhi[t][j + 4] = (__bf16)b[j];
        qlo[t][j + 4] = (__bf16)(b[j] - (float)qhi[t][j + 4]);
      }
    }
  }

  f32x4 o_acc[8];
#pragma unroll
  for (int c = 0; c < 8; ++c) o_acc[c] = (f32x4){0.f, 0.f, 0.f, 0.f};
  float m_r[4], l_r[4];
#pragma unroll
  for (int r4 = 0; r4 < 4; ++r4) { m_r[r4] = -INFINITY; l_r[r4] = 0.f; }

  for (int it = 0; it < SK / BN; ++it) {
    const int s0 = it * BN;

    // ---- S = Q K^T  (pure bf16 loads -> MFMA; no cvt on the dep chain)
    f32x4 sf[4];
#pragma unroll
    for (int n = 0; n < 4; ++n) sf[n] = (f32x4){0.f, 0.f, 0.f, 0.f};
#pragma unroll
    for (int n = 0; n < 4; ++n) {
      const size_t krow = (size_t)(s0 + 16 * n + i16) * D + 8 * quad;
#pragma unroll
      for (int t = 0; t < 4; ++t) {
        bf16x8 kh = *(const bf16x8*)(khb + krow + 32 * t);
        bf16x8 kl = *(const bf16x8*)(klb + krow + 32 * t);
        sf[n] = __builtin_amdgcn_mfma_f32_16x16x32_bf16(qhi[t], kh, sf[n], 0, 0, 0);
        sf[n] = __builtin_amdgcn_mfma_f32_16x16x32_bf16(qlo[t], kh, sf[n], 0, 0, 0);
        sf[n] = __builtin_amdgcn_mfma_f32_16x16x32_bf16(qhi[t], kl, sf[n], 0, 0, 0);
      }
    }

    // ---- online softmax (no 1/sqrt(D) scale, per reference)
    float alpha[4], rs[4];
#pragma unroll
    for (int r4 = 0; r4 < 4; ++r4) {
      float mx = fmaxf(fmaxf(sf[0][r4], sf[1][r4]), fmaxf(sf[2][r4], sf[3][r4]));
      mx = fmaxf(mx, __shfl_xor(mx, 1, 64));
      mx = fmaxf(mx, __shfl_xor(mx, 2, 64));
      mx = fmaxf(mx, __shfl_xor(mx, 4, 64));
      mx = fmaxf(mx, __shfl_xor(mx, 8, 64));
      const float mnew = fmaxf(m_r[r4], mx);
      alpha[r4] = __expf(m_r[r4] - mnew);   // first iter: exp(-inf)=0
      m_r[r4] = mnew;
      rs[r4] = 0.f;
    }
#pragma unroll
    for (int n = 0; n < 4; ++n) {
#pragma unroll
      for (int r4 = 0; r4 < 4; ++r4) {
        const float p = __expf(sf[n][r4] - m_r[r4]);
        const __bf16 pb = (__bf16)p;
        rs[r4] += (float)pb;   // l consistent with bf16 P fed to P*V
        Ps[(16 * wave + 4 * quad + r4) * PS_STRIDE + 16 * n + i16] = pb;
      }
    }
#pragma unroll
    for (int r4 = 0; r4 < 4; ++r4) {
      float s = rs[r4];
      s += __shfl_xor(s, 1, 64);
      s += __shfl_xor(s, 2, 64);
      s += __shfl_xor(s, 4, 64);
      s += __shfl_xor(s, 8, 64);
      l_r[r4] = l_r[r4] * alpha[r4] + s;
#pragma unroll
      for (int c = 0; c < 8; ++c) o_acc[c][r4] *= alpha[r4];
    }

    // Ps: same-wave DS ops retire in order; drain before fragment reads.
    asm volatile("s_waitcnt lgkmcnt(0)" ::: "memory");

    // ---- O += P V : V B-frags straight from transposed global (L1-shared by 4 waves)
    bf16x8 pf[2];
#pragma unroll
    for (int f = 0; f < 2; ++f)
      pf[f] = *(const bf16x8*)&Ps[(16 * wave + i16) * PS_STRIDE + 32 * f + 8 * quad];
#pragma unroll
    for (int c = 0; c < 8; ++c) {
#pragma unroll
      for (int f = 0; f < 2; ++f) {
        bf16x8 vf = *(const bf16x8*)(vtb + (size_t)(16 * c + i16) * SK + s0 + 32 * f + 8 * quad);
        o_acc[c] = __builtin_amdgcn_mfma_f32_16x16x32_bf16(pf[f], vf, o_acc[c], 0, 0, 0);
      }
    }
  }

  // ---- epilogue: divide by row sum, store fp32
  float* obase = outg + (size_t)bhg * (LQ * D) + (size_t)(qtile * BM) * D;
#pragma unroll
  for (int r4 = 0; r4 < 4; ++r4) {
    const float inv = 1.f / l_r[r4];
    float* op = obase + (size_t)(16 * wave + 4 * quad + r4) * D + i16;
#pragma unroll
    for (int c = 0; c < 8; ++c) op[16 * c] = o_acc[c][r4] * inv;
  }
}

extern "C" void kernel_launch(void* const* d_in, const int* in_sizes, int n_in,
                              void* d_out, int out_size, void* d_ws, size_t ws_size,
                              hipStream_t stream) {
  const float* q = (const float*)d_in[0];
  const float* k = (const float*)d_in[1];
  const float* v = (const float*)d_in[2];
  float* out = (float*)d_out;
  (void)in_sizes; (void)n_in; (void)out_size; (void)ws_size;

  const size_t kv_elems = (size_t)NKV * SK * D;          // 4.19M
  __bf16* khi = (__bf16*)d_ws;                           // 8.39 MB
  __bf16* klo = khi + kv_elems;                          // 8.39 MB
  __bf16* vt  = klo + kv_elems;                          // 8.39 MB  (total 25.2 MB)

  conv_k<<<dim3(kv_elems / (256 * 4)), 256, 0, stream>>>(k, khi, klo);   // 4096 blocks
  transpose_v<<<dim3(NKV * 64), 256, 0, stream>>>(v, vt);                // 1024 blocks
  gqa_fwd<<<dim3(64 * (LQ / BM)), 256, 0, stream>>>(q, khi, klo, vt, out);
}

// Round 6
// 506.435 us; speedup vs baseline: 3.2539x; 3.2539x over previous
//
#include <hip/hip_runtime.h>
#include <hip/hip_bf16.h>
#include <math.h>

typedef __bf16 bf16x8 __attribute__((ext_vector_type(8)));
typedef __bf16 bf16x4 __attribute__((ext_vector_type(4)));
typedef float f32x4 __attribute__((ext_vector_type(4)));

constexpr int D  = 128;
constexpr int LQ = 2048;
constexpr int SK = 2048;
constexpr int BM = 128;  // queries per block (4 waves x 32 rows)
constexpr int BN = 64;   // keys per iteration
constexpr int NKV = 16;  // B*H distinct KV heads

__device__ __forceinline__ void load_lds16(const void* g, void* l) {
  __builtin_amdgcn_global_load_lds((const __attribute__((address_space(1))) unsigned*)g,
                                   (__attribute__((address_space(3))) unsigned*)l, 16, 0, 0);
}

// ---- prologue A: K fp32 -> Khi/Klo bf16 (elementwise, coalesced)
__global__ __launch_bounds__(256) void conv_k(const float* __restrict__ k,
                                              __bf16* __restrict__ khi,
                                              __bf16* __restrict__ klo) {
  const size_t i = ((size_t)blockIdx.x * 256 + threadIdx.x) * 4;
  f32x4 a = *(const f32x4*)(k + i);
  bf16x4 hi, lo;
#pragma unroll
  for (int j = 0; j < 4; ++j) {
    hi[j] = (__bf16)a[j];
    lo[j] = (__bf16)(a[j] - (float)hi[j]);
  }
  *(bf16x4*)(khi + i) = hi;
  *(bf16x4*)(klo + i) = lo;
}

// ---- prologue B: V fp32 [bh][s][d] -> Vt bf16 [bh][d][s]
__global__ __launch_bounds__(256) void transpose_v(const float* __restrict__ v,
                                                   __bf16* __restrict__ vt) {
  const int b    = blockIdx.x;        // 1024 = 16 bh x 64
  const int bh   = b >> 6;
  const int blk2 = b & 63;
  const int t    = threadIdx.x;
  const int s0   = (blk2 * 2 + (t >> 7)) * 16;
  const int d    = t & 127;
  const float* src = v + ((size_t)bh * SK + s0) * D + d;
  bf16x8 o0, o1;
#pragma unroll
  for (int j = 0; j < 8; ++j) o0[j] = (__bf16)src[j * D];
#pragma unroll
  for (int j = 0; j < 8; ++j) o1[j] = (__bf16)src[(8 + j) * D];
  __bf16* dst = vt + ((size_t)bh * D + d) * SK + s0;
  *(bf16x8*)dst = o0;
  *(bf16x8*)(dst + 8) = o1;
}

// ---- main: m97-style flash GQA. LDS tiles staged by global_load_lds(16B) with
// XOR source-swizzle (conflict-free ds_read_b128). hi/lo bf16 split QK^T.
// Layouts (m89/m91/m120): A[m=lane&15][k=quad*8+j]; B[k=quad*8+j][n=lane&15];
// C/D: row=4*quad+r, col=lane&15.
__global__ __launch_bounds__(256, 2)
void gqa_fwd(const float* __restrict__ qg, const __bf16* __restrict__ khi_g,
             const __bf16* __restrict__ klo_g, const __bf16* __restrict__ vt_g,
             float* __restrict__ outg)
{
  // swizzled layouts: K*[s][chunk'=chunk^(s&15)] (16-chunk rows, 256B)
  //                   Vs[d][chunk'=chunk^(d&7)]  (8-chunk rows, 128B)
  //                   Ps[m][chunk'=chunk^(m&7)]  (8-chunk rows, 128B)
  __shared__ alignas(16) __bf16 Kh[BN * D];   // 16KB
  __shared__ alignas(16) __bf16 Kl[BN * D];   // 16KB
  __shared__ alignas(16) __bf16 Vs[D * BN];   // 16KB
  __shared__ alignas(16) __bf16 Ps[BM * BN];  // 16KB

  // XCD swizzle (bid%8 -> XCD heuristic): each XCD owns 2 KV heads -> ~3MB L2 set.
  const int bid   = blockIdx.x;
  const int xcd   = bid & 7;
  const int idx   = bid >> 3;           // 0..127
  const int bh    = 2 * xcd + (idx & 1);
  const int grp   = (idx >> 1) & 3;
  const int qtile = idx >> 3;           // 0..15
  const int bhg   = bh * 4 + grp;

  const int tid  = threadIdx.x;
  const int wave = tid >> 6;
  const int lane = tid & 63;
  const int i16  = lane & 15;
  const int quad = lane >> 4;

  const float*  qbase = qg + (size_t)bhg * (LQ * D) + (size_t)(qtile * BM) * D;
  const __bf16* khb   = khi_g + (size_t)bh * (SK * D);
  const __bf16* klb   = klo_g + (size_t)bh * (SK * D);
  const __bf16* vtb   = vt_g + (size_t)bh * (D * SK);   // [d][s]

  // ---- Q fragments, persistent hi/lo. Wave w owns rows [32w,32w+32), u-tiles of 16.
  bf16x8 qhi[2][4], qlo[2][4];
#pragma unroll
  for (int u = 0; u < 2; ++u) {
    const float* qp = qbase + (size_t)(32 * wave + 16 * u + i16) * D + 8 * quad;
#pragma unroll
    for (int t = 0; t < 4; ++t) {
      f32x4 a = *(const f32x4*)(qp + 32 * t);
      f32x4 b = *(const f32x4*)(qp + 32 * t + 4);
#pragma unroll
      for (int j = 0; j < 4; ++j) {
        qhi[u][t][j]     = (__bf16)a[j];
        qlo[u][t][j]     = (__bf16)(a[j] - (float)qhi[u][t][j]);
        qhi[u][t][j + 4] = (__bf16)b[j];
        qlo[u][t][j + 4] = (__bf16)(b[j] - (float)qhi[u][t][j + 4]);
      }
    }
  }

  f32x4 o_acc[2][8];
#pragma unroll
  for (int u = 0; u < 2; ++u)
#pragma unroll
    for (int c = 0; c < 8; ++c) o_acc[u][c] = (f32x4){0.f, 0.f, 0.f, 0.f};
  float m_r[2][4], l_r[2][4];
#pragma unroll
  for (int u = 0; u < 2; ++u)
#pragma unroll
    for (int r = 0; r < 4; ++r) { m_r[u][r] = -INFINITY; l_r[u][r] = 0.f; }

  for (int it = 0; it < SK / BN; ++it) {
    const int s0 = it * BN;
    __syncthreads();  // previous tile fully consumed

    // ---- async stage: 12 x global_load_lds(16B) per wave, src-swizzled
#pragma unroll
    for (int c = 0; c < 4; ++c) {
      const int wc = 4 * wave + c;  // wave-uniform chunk id 0..15 (1KB each)
      // K rows: 4 rows of 256B per wc
      const int srow = wc * 4 + (lane >> 4);
      const int jk   = (lane & 15) ^ (srow & 15);
      load_lds16(khb + (size_t)(s0 + srow) * D + 8 * jk, (char*)Kh + wc * 1024);
      load_lds16(klb + (size_t)(s0 + srow) * D + 8 * jk, (char*)Kl + wc * 1024);
      // V rows: 8 rows of 128B per wc
      const int drow = wc * 8 + (lane >> 3);
      const int jv   = (lane & 7) ^ (drow & 7);
      load_lds16(vtb + (size_t)drow * SK + s0 + 8 * jv, (char*)Vs + wc * 1024);
    }
    asm volatile("s_waitcnt vmcnt(0)" ::: "memory");
    __syncthreads();

    // ---- S = Q K^T (fragments from swizzled LDS; 2-way banks = free)
    f32x4 sf[2][4];
#pragma unroll
    for (int u = 0; u < 2; ++u)
#pragma unroll
      for (int n = 0; n < 4; ++n) sf[u][n] = (f32x4){0.f, 0.f, 0.f, 0.f};
#pragma unroll
    for (int n = 0; n < 4; ++n) {
#pragma unroll
      for (int t = 0; t < 4; ++t) {
        const int ke = (16 * n + i16) * 128 + 8 * ((4 * t + quad) ^ i16);
        bf16x8 kh = *(const bf16x8*)&Kh[ke];
        bf16x8 kl = *(const bf16x8*)&Kl[ke];
#pragma unroll
        for (int u = 0; u < 2; ++u) {
          sf[u][n] = __builtin_amdgcn_mfma_f32_16x16x32_bf16(qhi[u][t], kh, sf[u][n], 0, 0, 0);
          sf[u][n] = __builtin_amdgcn_mfma_f32_16x16x32_bf16(qlo[u][t], kh, sf[u][n], 0, 0, 0);
          sf[u][n] = __builtin_amdgcn_mfma_f32_16x16x32_bf16(qhi[u][t], kl, sf[u][n], 0, 0, 0);
        }
      }
    }

    // ---- online softmax (no 1/sqrt(D) scale, per reference)
#pragma unroll
    for (int u = 0; u < 2; ++u) {
      float alpha[4], rs[4];
#pragma unroll
      for (int r = 0; r < 4; ++r) {
        float mx = fmaxf(fmaxf(sf[u][0][r], sf[u][1][r]), fmaxf(sf[u][2][r], sf[u][3][r]));
        mx = fmaxf(mx, __shfl_xor(mx, 1, 64));
        mx = fmaxf(mx, __shfl_xor(mx, 2, 64));
        mx = fmaxf(mx, __shfl_xor(mx, 4, 64));
        mx = fmaxf(mx, __shfl_xor(mx, 8, 64));
        const float mnew = fmaxf(m_r[u][r], mx);
        alpha[r] = __expf(m_r[u][r] - mnew);   // first iter: exp(-inf)=0
        m_r[u][r] = mnew;
        rs[r] = 0.f;
      }
#pragma unroll
      for (int n = 0; n < 4; ++n) {
#pragma unroll
        for (int r = 0; r < 4; ++r) {
          const float p = __expf(sf[u][n][r] - m_r[u][r]);
          const __bf16 pb = (__bf16)p;
          rs[r] += (float)pb;   // l consistent with bf16 P fed to P*V
          const int ml = 32 * wave + 16 * u + 4 * quad + r;
          const int jp = (2 * n + (i16 >> 3)) ^ (ml & 7);
          Ps[ml * 64 + jp * 8 + (i16 & 7)] = pb;
        }
      }
#pragma unroll
      for (int r = 0; r < 4; ++r) {
        float s = rs[r];
        s += __shfl_xor(s, 1, 64);
        s += __shfl_xor(s, 2, 64);
        s += __shfl_xor(s, 4, 64);
        s += __shfl_xor(s, 8, 64);
        l_r[u][r] = l_r[u][r] * alpha[r] + s;
#pragma unroll
        for (int c = 0; c < 8; ++c) o_acc[u][c][r] *= alpha[r];
      }
    }

    // Ps rows are wave-local; same-wave DS ops retire in order -> drain only.
    asm volatile("s_waitcnt lgkmcnt(0)" ::: "memory");

    // ---- O += P V
    bf16x8 pf[2][2];
#pragma unroll
    for (int u = 0; u < 2; ++u)
#pragma unroll
      for (int f = 0; f < 2; ++f)
        pf[u][f] = *(const bf16x8*)&Ps[(32 * wave + 16 * u + i16) * 64 +
                                       8 * ((4 * f + quad) ^ (i16 & 7))];
#pragma unroll
    for (int c = 0; c < 8; ++c) {
#pragma unroll
      for (int f = 0; f < 2; ++f) {
        bf16x8 vf = *(const bf16x8*)&Vs[(16 * c + i16) * 64 +
                                        8 * ((4 * f + quad) ^ (i16 & 7))];
#pragma unroll
        for (int u = 0; u < 2; ++u)
          o_acc[u][c] = __builtin_amdgcn_mfma_f32_16x16x32_bf16(pf[u][f], vf, o_acc[u][c], 0, 0, 0);
      }
    }
  }

  // ---- epilogue: divide by row sum, store fp32
  float* obase = outg + (size_t)bhg * (LQ * D) + (size_t)(qtile * BM) * D;
#pragma unroll
  for (int u = 0; u < 2; ++u)
#pragma unroll
    for (int r = 0; r < 4; ++r) {
      const float inv = 1.f / l_r[u][r];
      float* op = obase + (size_t)(32 * wave + 16 * u + 4 * quad + r) * D + i16;
#pragma unroll
      for (int c = 0; c < 8; ++c) op[16 * c] = o_acc[u][c][r] * inv;
    }
}

extern "C" void kernel_launch(void* const* d_in, const int* in_sizes, int n_in,
                              void* d_out, int out_size, void* d_ws, size_t ws_size,
                              hipStream_t stream) {
  const float* q = (const float*)d_in[0];
  const float* k = (const float*)d_in[1];
  const float* v = (const float*)d_in[2];
  float* out = (float*)d_out;
  (void)in_sizes; (void)n_in; (void)out_size; (void)ws_size;

  const size_t kv_elems = (size_t)NKV * SK * D;          // 4.19M
  __bf16* khi = (__bf16*)d_ws;                           // 8.39 MB
  __bf16* klo = khi + kv_elems;                          // 8.39 MB
  __bf16* vt  = klo + kv_elems;                          // 8.39 MB

  conv_k<<<dim3(kv_elems / (256 * 4)), 256, 0, stream>>>(k, khi, klo);
  transpose_v<<<dim3(NKV * 64), 256, 0, stream>>>(v, vt);
  gqa_fwd<<<dim3(64 * (LQ / BM)), 256, 0, stream>>>(q, khi, klo, vt, out);
}